// Round 7
// baseline (41183.868 us; speedup 1.0000x reference)
//
#include <hip/hip_runtime.h>
#include <stdint.h>

#define HH 640
#define BB 128
#define TT 512
#define VV 4097
#define G4 2560
#define VE 4112
#define NT2 26
#define NC2p (NT2*128)   // 3328 (tiles 0..24 real, 25 dummy-zero)
#define NT3 34
#define NC3p (NT3*128)   // 4352 (tiles 0..32 real, 33 dummy-zero)

__device__ __forceinline__ float sigm(float x){ return 1.0f/(1.0f+expf(-x)); }

__device__ __forceinline__ unsigned long long packkey(float f, unsigned v){
    unsigned u = __float_as_uint(f);
    unsigned m = (u & 0x80000000u) ? ~u : (u | 0x80000000u);
    return ((unsigned long long)m << 32) | (unsigned long long)(~v);
}
__device__ __forceinline__ float vld(const float* p){ return *(const volatile float*)p; }
__device__ __forceinline__ void  vst(float* p, float v){ *(volatile float*)p = v; }
__device__ __forceinline__ float aldf(const float* p){
    unsigned u = __hip_atomic_load((const unsigned*)p, __ATOMIC_RELAXED, __HIP_MEMORY_SCOPE_AGENT);
    return __uint_as_float(u);
}
__device__ __forceinline__ void astf(float* p, float v){
    __hip_atomic_store((unsigned*)p, __float_as_uint(v), __ATOMIC_RELAXED, __HIP_MEMORY_SCOPE_AGENT);
}

// ---------------- init ----------------
__global__ __launch_bounds__(256) void k_init5(const float* __restrict__ h0, const float* __restrict__ c0,
                       float* __restrict__ hA, float* __restrict__ cA,
                       int* __restrict__ label, unsigned long long* __restrict__ slot,
                       int* __restrict__ ctrl){
    int i = blockIdx.x*256 + threadIdx.x;
    if (i < BB*HH){
        int b = i / HH, jj = i % HH;
        size_t o = (size_t)jj*128 + b;
        hA[o] = h0[i]; cA[o] = c0[i];
    }
    if (i < BB){ slot[i] = 0ULL; label[i] = 0; }
    if (i < 2048) ctrl[i] = 0;
}

// ---------------- one-time transposes / packs ----------------
__global__ __launch_bounds__(256) void k_tr_gate(const float* __restrict__ W, float* __restrict__ WT){
    int idx = blockIdx.x*256 + threadIdx.x;
    if (idx >= G4*160) return;
    int row = idx / 160, kq = idx % 160;
    int g = row / HH, jj = row % HH;
    float4 f = *reinterpret_cast<const float4*>(W + (size_t)row*HH + kq*4);
    WT[(size_t)(kq*4+0)*G4 + jj*4+g] = f.x;
    WT[(size_t)(kq*4+1)*G4 + jj*4+g] = f.y;
    WT[(size_t)(kq*4+2)*G4 + jj*4+g] = f.z;
    WT[(size_t)(kq*4+3)*G4 + jj*4+g] = f.w;
}
__global__ __launch_bounds__(256) void k_tr640(const float* __restrict__ W, float* __restrict__ WT){
    int idx = blockIdx.x*256 + threadIdx.x;
    if (idx >= HH*160) return;
    int n = idx / 160, kq = idx % 160;
    float4 f = *reinterpret_cast<const float4*>(W + (size_t)n*HH + kq*4);
    WT[(size_t)(kq*4+0)*HH + n] = f.x;
    WT[(size_t)(kq*4+1)*HH + n] = f.y;
    WT[(size_t)(kq*4+2)*HH + n] = f.z;
    WT[(size_t)(kq*4+3)*HH + n] = f.w;
}
__global__ __launch_bounds__(256) void k_tr_embT(const float* __restrict__ emb, float* __restrict__ embT){
    int idx = blockIdx.x*256 + threadIdx.x;
    if (idx >= 160*VE) return;
    int kq = idx / VE, v = idx % VE;
    float4 f = make_float4(0.f,0.f,0.f,0.f);
    if (v < VV) f = *reinterpret_cast<const float4*>(emb + (size_t)v*HH + kq*4);
    embT[(size_t)(kq*4+0)*VE + v] = f.x;
    embT[(size_t)(kq*4+1)*VE + v] = f.y;
    embT[(size_t)(kq*4+2)*VE + v] = f.z;
    embT[(size_t)(kq*4+3)*VE + v] = f.w;
}
// WJ [k4][3328][4]: u<2560 gates (u=jj*4+g), 2560..3199 joint, rest zero
__global__ __launch_bounds__(256) void k_tr_WJp(const float* __restrict__ Whh, const float* __restrict__ Wpred,
                        float* __restrict__ WJ){
    int idx = blockIdx.x*256 + threadIdx.x;
    if (idx >= NC2p*160) return;
    int u = idx / 160, k4 = idx % 160;
    float4 f = make_float4(0.f,0.f,0.f,0.f);
    if (u < G4){
        int jj = u >> 2, g = u & 3;
        f = *reinterpret_cast<const float4*>(Whh + (size_t)(g*HH+jj)*HH + k4*4);
    } else if (u < 3200){
        f = *reinterpret_cast<const float4*>(Wpred + (size_t)(u-G4)*HH + k4*4);
    }
    float* d = WJ + ((size_t)k4*NC2p + u)*4;
    d[0]=f.x; d[1]=f.y; d[2]=f.z; d[3]=f.w;
}
// WoutK4 [k4][4352][4]: cols 0..4096 real, rest zero
__global__ __launch_bounds__(256) void k_tr_woutp(const float* __restrict__ Wout, float* __restrict__ WK){
    int idx = blockIdx.x*256 + threadIdx.x;
    if (idx >= NC3p*160) return;
    int v = idx / 160, k4 = idx % 160;
    float4 f = make_float4(0.f,0.f,0.f,0.f);
    if (v < VV) f = *reinterpret_cast<const float4*>(Wout + (size_t)v*HH + k4*4);
    float* d = WK + ((size_t)k4*NC3p + v)*4;
    d[0]=f.x; d[1]=f.y; d[2]=f.z; d[3]=f.w;
}
__global__ __launch_bounds__(256) void k_boutp(const float* __restrict__ b_out, float* __restrict__ bp){
    int v = blockIdx.x*256 + threadIdx.x;
    if (v < NC3p) bp[v] = (v < VV) ? b_out[v] : -1e30f;
}

// ---------------- emb_proj: [VV+1][2560]; row VV = bias-only ----------------
typedef float f32x4v __attribute__((ext_vector_type(4)));
__global__ __launch_bounds__(256) void k_embproj3(const float* __restrict__ embT,
                          const float* __restrict__ WihT,
                          const float* __restrict__ b_ih, const float* __restrict__ b_hh,
                          float* __restrict__ embproj){
    __shared__ float lwv[HH*16];
    int vt = blockIdx.x / 160, ut = blockIdx.x % 160;
    for (int i=threadIdx.x; i<HH*16; i+=256)
        lwv[i] = WihT[(size_t)(i>>4)*G4 + ut*16 + (i&15)];
    float bias[16];
    #pragma unroll
    for (int u=0;u<16;++u){
        int gu = ut*16+u, jj = gu>>2, g = gu&3;
        bias[u] = b_ih[g*HH+jj] + b_hh[g*HH+jj];
    }
    __syncthreads();
    int v = vt*256 + threadIdx.x;
    float acc[16];
    #pragma unroll
    for (int u=0;u<16;++u) acc[u]=0.f;
    if (v < VV){
        #pragma unroll 2
        for (int k=0;k<HH;++k){
            float e = embT[(size_t)k*VE + v];
            const f32x4v* wr = reinterpret_cast<const f32x4v*>(&lwv[k*16]);
            #pragma unroll
            for (int g=0; g<4; ++g){
                f32x4v w = wr[g];
                #pragma unroll
                for (int ee=0; ee<4; ++ee) acc[g*4+ee] = fmaf(w[ee], e, acc[g*4+ee]);
            }
        }
    }
    if (v <= VV){
        #pragma unroll
        for (int q=0;q<4;++q){
            float4 st = make_float4(acc[q*4+0]+bias[q*4+0], acc[q*4+1]+bias[q*4+1],
                                    acc[q*4+2]+bias[q*4+2], acc[q*4+3]+bias[q*4+3]);
            *reinterpret_cast<float4*>(embproj + (size_t)v*G4 + ut*16 + q*4) = st;
        }
    }
}

// ---------------- enc_proj precompute, layout [t][n][b] ----------------
__global__ __launch_bounds__(128) void k_encprojT2(const float* __restrict__ x,
                          const float* __restrict__ WencT, const float* __restrict__ b_enc,
                          float* __restrict__ encprojT){
    int tile = (blockIdx.x & 7)*2560 + (blockIdx.x >> 3);
    int b   = tile / 160;
    int rem = tile % 160;
    int tt  = rem / 5;
    int nt2 = rem % 5;
    int n = nt2*128 + threadIdx.x;
    float acc[16];
    #pragma unroll
    for (int i=0;i<16;i++) acc[i]=0.f;
    const float* xb = x + (size_t)b*HH*TT + tt*16;
    #pragma unroll 4
    for (int k=0;k<HH;++k){
        float wv = WencT[(size_t)k*HH + n];
        const float4* xp = reinterpret_cast<const float4*>(xb + (size_t)k*TT);
        float4 x0=xp[0], x1=xp[1], x2=xp[2], x3=xp[3];
        acc[0]=fmaf(x0.x,wv,acc[0]);  acc[1]=fmaf(x0.y,wv,acc[1]);
        acc[2]=fmaf(x0.z,wv,acc[2]);  acc[3]=fmaf(x0.w,wv,acc[3]);
        acc[4]=fmaf(x1.x,wv,acc[4]);  acc[5]=fmaf(x1.y,wv,acc[5]);
        acc[6]=fmaf(x1.z,wv,acc[6]);  acc[7]=fmaf(x1.w,wv,acc[7]);
        acc[8]=fmaf(x2.x,wv,acc[8]);  acc[9]=fmaf(x2.y,wv,acc[9]);
        acc[10]=fmaf(x2.z,wv,acc[10]); acc[11]=fmaf(x2.w,wv,acc[11]);
        acc[12]=fmaf(x3.x,wv,acc[12]); acc[13]=fmaf(x3.y,wv,acc[13]);
        acc[14]=fmaf(x3.z,wv,acc[14]); acc[15]=fmaf(x3.w,wv,acc[15]);
    }
    float be = b_enc[n];
    #pragma unroll
    for (int ti=0; ti<16; ++ti)
        encprojT[((size_t)(tt*16+ti)*HH + n)*BB + b] = acc[ti] + be;
}

// ---------------- gA init: gates(t=0) = Whh @ h0 ----------------
__global__ __launch_bounds__(512) void k_gA0(const float* __restrict__ WJ, const float* __restrict__ h0,
                       float* __restrict__ gA){
    __shared__ float stage[5120];
    __shared__ float red[3*128*33];
    int q = blockIdx.x >> 4, bg = blockIdx.x & 15;   // 5 quads x 16 bgroups
    const int tid = threadIdx.x;
    for (int i=tid; i<5120; i+=512){
        int jj = i>>3, bl = i&7;
        int k4 = jj>>2, ks = jj&3;
        stage[k4*32 + bl*4 + ks] = h0[(size_t)(bg*8+bl)*HH + jj];
    }
    __syncthreads();
    const int lane = tid & 127, kq = tid >> 7;
    float acc[4][8];
    #pragma unroll
    for (int c=0;c<4;++c)
        #pragma unroll
        for (int bl=0;bl<8;++bl) acc[c][bl]=0.f;
    const float* wp[4];
    #pragma unroll
    for (int c=0;c<4;++c)
        wp[c] = WJ + ((size_t)(kq*40)*NC2p + (q*4+c)*128 + lane)*4;
    for (int it=0; it<40; ++it){
        float4 wv[4];
        #pragma unroll
        for (int c=0;c<4;++c){ wv[c] = *reinterpret_cast<const float4*>(wp[c]); wp[c] += (size_t)NC2p*4; }
        const float4* hp4 = reinterpret_cast<const float4*>(&stage[(kq*40+it)*32]);
        float4 hv[8];
        #pragma unroll
        for (int bl=0;bl<8;++bl) hv[bl] = hp4[bl];
        #pragma unroll
        for (int c=0;c<4;++c)
            #pragma unroll
            for (int bl=0;bl<8;++bl){
                acc[c][bl] = fmaf(wv[c].x, hv[bl].x, acc[c][bl]);
                acc[c][bl] = fmaf(wv[c].y, hv[bl].y, acc[c][bl]);
                acc[c][bl] = fmaf(wv[c].z, hv[bl].z, acc[c][bl]);
                acc[c][bl] = fmaf(wv[c].w, hv[bl].w, acc[c][bl]);
            }
    }
    if (kq > 0){
        #pragma unroll
        for (int c=0;c<4;++c)
            #pragma unroll
            for (int bl=0;bl<8;++bl)
                red[(kq-1)*4224 + lane*33 + c*8+bl] = acc[c][bl];
    }
    __syncthreads();
    if (kq == 0){
        #pragma unroll
        for (int c=0;c<4;++c){
            int u = (q*4+c)*128 + lane;
            int jj = u >> 2, g = u & 3;
            #pragma unroll
            for (int bl=0;bl<8;++bl){
                float s = acc[c][bl] + red[lane*33+c*8+bl] + red[4224+lane*33+c*8+bl] + red[8448+lane*33+c*8+bl];
                gA[((size_t)jj*128 + bg*8+bl)*4 + g] = s;
            }
        }
    }
}

// ================= persistent col-partitioned kernel =================
__global__ __launch_bounds__(512,1) void k_run2(
    const float* __restrict__ WJ, const float* __restrict__ WoutK4,
    const float* __restrict__ b_pred, const float* __restrict__ boutP,
    const float* __restrict__ embproj, const float* __restrict__ encprojT,
    const int* __restrict__ lens,
    float* gA, float* gB,
    float* cA, float* cB, float* hA,
    float* h1G, float* jointG,
    unsigned long long* slot, int* label,
    int* ctrl, float* dout)
{
    __shared__ float stage[5120];               // 20.5 KB
    __shared__ float red[3*128*33];             // 50.7 KB
    __shared__ unsigned long long keys[128*9];  //  9.2 KB
    const int tid = threadIdx.x;
    int xcd = __builtin_amdgcn_s_getreg(63508) & 7;

    __shared__ int s_r, s_R;
    if (tid == 0){
        s_r = (int)__hip_atomic_fetch_add((unsigned*)&ctrl[xcd], 1u, __ATOMIC_RELAXED, __HIP_MEMORY_SCOPE_AGENT);
        __hip_atomic_fetch_add((unsigned*)&ctrl[16], 1u, __ATOMIC_RELAXED, __HIP_MEMORY_SCOPE_AGENT);
        long spin = 0;
        while (__hip_atomic_load((unsigned*)&ctrl[16], __ATOMIC_RELAXED, __HIP_MEMORY_SCOPE_AGENT) < 256u
               && spin < 400000000L){ __builtin_amdgcn_s_sleep(1); ++spin; }
        s_R = (int)__hip_atomic_load((unsigned*)&ctrl[xcd], __ATOMIC_RELAXED, __HIP_MEMORY_SCOPE_AGENT);
    }
    __syncthreads();
    const int r = s_r, R = s_R;

    unsigned* la = (unsigned*)&ctrl[64 + xcd*64];
    unsigned* lr = (unsigned*)&ctrl[64 + xcd*64 + 16];
    unsigned* ga = (unsigned*)&ctrl[1024];

    // tile ownership
    int p2t[4];
    p2t[0] = xcd; p2t[1] = xcd+8; p2t[2] = 16+xcd; p2t[3] = (xcd==0) ? 24 : -1;
    const int njj = (xcd<4) ? 96 : 64;
    int jbase[3];
    jbase[0] = xcd*32; jbase[1] = (xcd+8)*32; jbase[2] = (16+xcd)*32;
    const int NA3 = (xcd==0) ? 32 : 16;

    unsigned ph = 0;
    #define LBARG() do { \
        asm volatile("s_waitcnt vmcnt(0) lgkmcnt(0)" ::: "memory"); \
        __syncthreads(); \
        ++ph; \
        if (tid == 0){ \
            unsigned n = __hip_atomic_fetch_add(la, 1u, __ATOMIC_RELAXED, __HIP_MEMORY_SCOPE_AGENT) + 1u; \
            if (n == ph*(unsigned)R){ \
                __hip_atomic_fetch_add(ga, 1u, __ATOMIC_RELAXED, __HIP_MEMORY_SCOPE_AGENT); \
                long spin = 0; \
                while (__hip_atomic_load(ga, __ATOMIC_RELAXED, __HIP_MEMORY_SCOPE_AGENT) < ph*8u \
                       && spin < 400000000L){ __builtin_amdgcn_s_sleep(1); ++spin; } \
                __hip_atomic_store(lr, ph, __ATOMIC_RELAXED, __HIP_MEMORY_SCOPE_AGENT); \
            } else { \
                long spin = 0; \
                while (__hip_atomic_load(lr, __ATOMIC_RELAXED, __HIP_MEMORY_SCOPE_AGENT) < ph \
                       && spin < 400000000L){ __builtin_amdgcn_s_sleep(1); ++spin; } \
            } \
        } \
        __syncthreads(); \
        asm volatile("" ::: "memory"); \
    } while(0)

    for (int t = 0; t < TT; ++t){
        // ---------- P1: select + LSTM nonlin (jj-partition, all 128 b) ----------
        {
            int tot = njj*128;
            for (int i = r*512 + tid; i < tot; i += R*512){
                int jjl = i >> 7, b = i & 127;
                int jj = jbase[jjl>>5] + (jjl & 31);
                bool mask; int sel = 0, kprev = 0;
                if (t == 0){ mask = true; sel = 0; }
                else {
                    unsigned long long key = __hip_atomic_load(&slot[b], __ATOMIC_RELAXED, __HIP_MEMORY_SCOPE_AGENT);
                    int k = (int)(~(unsigned)key);
                    int lab = __hip_atomic_load(&label[b], __ATOMIC_RELAXED, __HIP_MEMORY_SCOPE_AGENT);
                    mask = ((t-1) >= lens[b]) || (k == 0);
                    kprev = k; sel = mask ? lab : k;
                }
                size_t o = (size_t)jj*128 + b;
                size_t o4 = o*4;
                const float* gs = (mask ? gA : gB) + o4;
                float gi = vld(gs+0), gf = vld(gs+1), gg = vld(gs+2), go = vld(gs+3);
                if (!mask){ float* gd = gA + o4; vst(gd+0,gi); vst(gd+1,gf); vst(gd+2,gg); vst(gd+3,go); }
                int erow = (t == 0) ? VV : sel;
                const float* ep = embproj + (size_t)erow*G4 + jj*4;
                gi += ep[0]; gf += ep[1]; gg += ep[2]; go += ep[3];
                float ce = mask ? vld(cA+o) : vld(cB+o);
                float cv = sigm(gf)*ce + sigm(gi)*tanhf(gg);
                float h2 = sigm(go)*tanhf(cv);
                float hprev = mask ? vld(hA+o) : aldf(&h1G[o]);
                vst(cA+o, ce); vst(cB+o, cv); vst(hA+o, hprev);
                astf(&h1G[o], h2);
                if (jj == 0){
                    if (t > 0) dout[(size_t)b*TT + (t-1)] = mask ? 0.f : (float)kprev;
                    __hip_atomic_store(&label[b], sel, __ATOMIC_RELAXED, __HIP_MEMORY_SCOPE_AGENT);
                }
            }
        }
        LBARG();

        // ---------- P2: gates+joint GEMM (col slice, all b via 16 bgroups) ----------
        if (r == 0 && tid < 128)
            __hip_atomic_store(&slot[tid], 0ULL, __ATOMIC_RELAXED, __HIP_MEMORY_SCOPE_AGENT);
        for (int a = r; a < 16; a += R){
            int bg = a;
            __syncthreads();
            for (int i = tid; i < 5120; i += 512){
                int jj = i>>3, bl = i&7;
                int k4 = jj>>2, ks = jj&3;
                stage[k4*32 + bl*4 + ks] = aldf(&h1G[(size_t)jj*128 + bg*8 + bl]);
            }
            __syncthreads();
            const int lane = tid & 127, kq = tid >> 7;
            float acc[4][8];
            #pragma unroll
            for (int c=0;c<4;++c)
                #pragma unroll
                for (int bl=0;bl<8;++bl) acc[c][bl]=0.f;
            const float* wp[4];
            #pragma unroll
            for (int c=0;c<4;++c){
                int tq = p2t[c];
                wp[c] = WJ + ((size_t)(kq*40)*NC2p + ((tq<0)?25:tq)*128 + lane)*4;
            }
            for (int it=0; it<40; ++it){
                float4 wv[4];
                #pragma unroll
                for (int c=0;c<4;++c){ wv[c] = *reinterpret_cast<const float4*>(wp[c]); wp[c] += (size_t)NC2p*4; }
                const float4* hp4 = reinterpret_cast<const float4*>(&stage[(kq*40+it)*32]);
                float4 hv[8];
                #pragma unroll
                for (int bl=0;bl<8;++bl) hv[bl] = hp4[bl];
                #pragma unroll
                for (int c=0;c<4;++c)
                    #pragma unroll
                    for (int bl=0;bl<8;++bl){
                        acc[c][bl] = fmaf(wv[c].x, hv[bl].x, acc[c][bl]);
                        acc[c][bl] = fmaf(wv[c].y, hv[bl].y, acc[c][bl]);
                        acc[c][bl] = fmaf(wv[c].z, hv[bl].z, acc[c][bl]);
                        acc[c][bl] = fmaf(wv[c].w, hv[bl].w, acc[c][bl]);
                    }
            }
            if (kq > 0){
                #pragma unroll
                for (int c=0;c<4;++c)
                    #pragma unroll
                    for (int bl=0;bl<8;++bl)
                        red[(kq-1)*4224 + lane*33 + c*8+bl] = acc[c][bl];
            }
            __syncthreads();
            if (kq == 0){
                #pragma unroll
                for (int c=0;c<4;++c){
                    int tq = p2t[c];
                    if (tq < 0) continue;
                    int u = tq*128 + lane;
                    #pragma unroll
                    for (int bl=0;bl<8;++bl){
                        float s = acc[c][bl] + red[lane*33+c*8+bl] + red[4224+lane*33+c*8+bl] + red[8448+lane*33+c*8+bl];
                        int b = bg*8 + bl;
                        if (u < G4){
                            vst(&gB[((size_t)(u>>2)*128 + b)*4 + (u&3)], s);
                        } else {
                            int n = u - G4;
                            float jv = fmaxf(s + b_pred[n] + encprojT[((size_t)t*HH + n)*BB + b], 0.f);
                            astf(&jointG[(size_t)n*128 + b], jv);
                        }
                    }
                }
            }
            __syncthreads();
        }
        LBARG();

        // ---------- P3: logits GEMM + argmax (vocab slice) ----------
        for (int a = r; a < NA3; a += R){
            int qi = a >> 4, bg = a & 15;
            __syncthreads();
            for (int i = tid; i < 5120; i += 512){
                int jj = i>>3, bl = i&7;
                int k4 = jj>>2, ks = jj&3;
                stage[k4*32 + bl*4 + ks] = aldf(&jointG[(size_t)jj*128 + bg*8 + bl]);
            }
            __syncthreads();
            const int lane = tid & 127, kq = tid >> 7;
            int q3[4];
            if (qi == 0){ q3[0]=xcd; q3[1]=xcd+8; q3[2]=xcd+16; q3[3]=xcd+24; }
            else        { q3[0]=32;  q3[1]=-1;    q3[2]=-1;     q3[3]=-1; }
            float acc[4][8];
            #pragma unroll
            for (int c=0;c<4;++c)
                #pragma unroll
                for (int bl=0;bl<8;++bl) acc[c][bl]=0.f;
            const float* wp[4];
            #pragma unroll
            for (int c=0;c<4;++c){
                int tq = q3[c];
                wp[c] = WoutK4 + ((size_t)(kq*40)*NC3p + ((tq<0)?33:tq)*128 + lane)*4;
            }
            for (int it=0; it<40; ++it){
                float4 wv[4];
                #pragma unroll
                for (int c=0;c<4;++c){ wv[c] = *reinterpret_cast<const float4*>(wp[c]); wp[c] += (size_t)NC3p*4; }
                const float4* hp4 = reinterpret_cast<const float4*>(&stage[(kq*40+it)*32]);
                float4 hv[8];
                #pragma unroll
                for (int bl=0;bl<8;++bl) hv[bl] = hp4[bl];
                #pragma unroll
                for (int c=0;c<4;++c)
                    #pragma unroll
                    for (int bl=0;bl<8;++bl){
                        acc[c][bl] = fmaf(wv[c].x, hv[bl].x, acc[c][bl]);
                        acc[c][bl] = fmaf(wv[c].y, hv[bl].y, acc[c][bl]);
                        acc[c][bl] = fmaf(wv[c].z, hv[bl].z, acc[c][bl]);
                        acc[c][bl] = fmaf(wv[c].w, hv[bl].w, acc[c][bl]);
                    }
            }
            if (kq > 0){
                #pragma unroll
                for (int c=0;c<4;++c)
                    #pragma unroll
                    for (int bl=0;bl<8;++bl)
                        red[(kq-1)*4224 + lane*33 + c*8+bl] = acc[c][bl];
            }
            __syncthreads();
            if (kq == 0){
                #pragma unroll
                for (int bl=0;bl<8;++bl){
                    unsigned long long best = 0ULL;
                    #pragma unroll
                    for (int c=0;c<4;++c){
                        int tq = q3[c];
                        if (tq < 0) continue;
                        int v = tq*128 + lane;
                        float s = acc[c][bl] + red[lane*33+c*8+bl] + red[4224+lane*33+c*8+bl] + red[8448+lane*33+c*8+bl] + boutP[v];
                        unsigned long long kk = packkey(s, (unsigned)v);
                        if (kk > best) best = kk;
                    }
                    keys[lane*9 + bl] = best;
                }
            }
            __syncthreads();
            if (tid < 8){
                unsigned long long best = 0ULL;
                for (int l=0; l<128; ++l){
                    unsigned long long kk = keys[l*9 + tid];
                    if (kk > best) best = kk;
                }
                __hip_atomic_fetch_max(&slot[bg*8 + tid], best, __ATOMIC_RELAXED, __HIP_MEMORY_SCOPE_AGENT);
            }
            __syncthreads();
        }
        LBARG();
    }
    #undef LBARG
}

// ---------------- final: emit t=511, hF, cF ----------------
__global__ __launch_bounds__(256) void kFin3(const int* __restrict__ lens,
                        const unsigned long long* __restrict__ slot,
                        const float* __restrict__ hA, const float* __restrict__ h1G,
                        const float* __restrict__ cA, const float* __restrict__ cB,
                        float* __restrict__ dout)
{
    int i = blockIdx.x*256 + threadIdx.x;
    if (i >= BB*HH) return;
    int b = i / HH, jj = i % HH;
    size_t o = (size_t)jj*128 + b;
    unsigned long long key = slot[b];
    int k = (int)(~(unsigned)key);
    bool m = ((TT-1) >= lens[b]) || (k == 0);
    dout[BB*TT + i]         = m ? hA[o] : h1G[o];
    dout[BB*TT + BB*HH + i] = m ? cA[o] : cB[o];
    if (i < BB){
        unsigned long long key2 = slot[i];
        int k2 = (int)(~(unsigned)key2);
        bool mm = ((TT-1) >= lens[i]) || (k2 == 0);
        dout[(size_t)i*TT + (TT-1)] = mm ? 0.0f : (float)k2;
    }
}

// ================= fallback (small ws): basic per-step kernels =================
__global__ __launch_bounds__(256) void k_init(const float* __restrict__ h0, const float* __restrict__ c0,
                       float* __restrict__ hs0, float* __restrict__ cso,
                       int* __restrict__ label, unsigned long long* __restrict__ slot){
    int i = blockIdx.x*256 + threadIdx.x;
    if (i < BB*HH){ hs0[i] = h0[i]; cso[i] = c0[i]; }
    if (i < BB){ label[i] = 0; slot[i] = 0ULL; }
}

__global__ __launch_bounds__(256) void k_p1o(
    const float* __restrict__ Whh, const float* __restrict__ Wih,
    const float* __restrict__ embedding,
    const float* __restrict__ b_ih, const float* __restrict__ b_hh,
    const int* __restrict__ lens,
    const float* __restrict__ hs_r, float* __restrict__ hs_w,
    const float* __restrict__ h1_r, float* __restrict__ h1_w,
    float* c_state, float* c1o, int* label,
    const unsigned long long* __restrict__ slot,
    float* __restrict__ out_emit, int t)
{
    int tile = (blockIdx.x & 7)*20 + (blockIdx.x >> 3);
    int jt = tile >> 4, bg = tile & 15;
    int lane = threadIdx.x & 63, w = threadIdx.x >> 6;
    int j = (jt<<6) + lane, b0 = bg<<3;

    bool mask[8]; int kprev[8]; int sel[8];
    #pragma unroll
    for (int bi=0; bi<8; ++bi){
        int b = b0+bi;
        if (t == 0){ mask[bi]=true; sel[bi]=0; kprev[bi]=0; }
        else {
            unsigned long long key = slot[b];
            int k = (int)(~(unsigned)key);
            int lab = label[b];
            bool m = ((t-1) >= lens[b]) || (k == 0);
            mask[bi]=m; kprev[bi]=k; sel[bi] = m ? lab : k;
        }
    }
    float acc[8];
    #pragma unroll
    for (int i=0;i<8;i++) acc[i]=0.f;
    const float* wrow  = Whh + (size_t)(w*HH + j)*HH;
    const float* wrow2 = Wih + (size_t)(w*HH + j)*HH;
    for (int kc=0; kc<HH; kc+=16){
        float wv[16], wv2[16];
        #pragma unroll
        for (int q=0;q<4;q++){
            float4 f = *reinterpret_cast<const float4*>(wrow + kc + q*4);
            wv[q*4+0]=f.x; wv[q*4+1]=f.y; wv[q*4+2]=f.z; wv[q*4+3]=f.w;
            float4 f2 = *reinterpret_cast<const float4*>(wrow2 + kc + q*4);
            wv2[q*4+0]=f2.x; wv2[q*4+1]=f2.y; wv2[q*4+2]=f2.z; wv2[q*4+3]=f2.w;
        }
        #pragma unroll
        for (int bi=0; bi<8; ++bi){
            int b = b0+bi;
            const float* hp0 = hs_r + (size_t)b*HH + kc;
            const float* hp1 = h1_r + (size_t)b*HH + kc;
            float a = acc[bi];
            if (mask[bi]){
                #pragma unroll
                for (int k=0;k<16;k++) a = fmaf(hp0[k], wv[k], a);
            } else {
                #pragma unroll
                for (int k=0;k<16;k++) a = fmaf(hp1[k], wv[k], a);
            }
            if (t > 0){
                const float* ep = embedding + (size_t)sel[bi]*HH + kc;
                #pragma unroll
                for (int k=0;k<16;k++) a = fmaf(ep[k], wv2[k], a);
            }
            acc[bi] = a;
        }
    }
    __shared__ float xch[8][4][64];
    #pragma unroll
    for (int bi=0; bi<8; ++bi)
        xch[bi][w][lane] = acc[bi] + b_ih[w*HH + j] + b_hh[w*HH + j];
    __syncthreads();
    #pragma unroll
    for (int rr=0; rr<2; ++rr){
        int bi = (w<<1) + rr;
        int b  = b0 + bi;
        size_t o = (size_t)b*HH + j;
        float gi = xch[bi][0][lane], gf = xch[bi][1][lane];
        float gg = xch[bi][2][lane], go = xch[bi][3][lane];
        float ce = mask[bi] ? c_state[o] : c1o[o];
        float c2 = sigm(gf)*ce + sigm(gi)*tanhf(gg);
        float h2 = sigm(go)*tanhf(c2);
        float he = mask[bi] ? hs_r[o] : h1_r[o];
        c_state[o] = ce; c1o[o] = c2; hs_w[o] = he; h1_w[o] = h2;
    }
    if (jt == 0 && t > 0 && threadIdx.x < 8){
        int bi = threadIdx.x; int b = b0 + bi;
        out_emit[(size_t)b*TT + (t-1)] = mask[bi] ? 0.0f : (float)kprev[bi];
        label[b] = sel[bi];
    }
}

__global__ __launch_bounds__(128) void k_p2o(
    const float* __restrict__ Wpred, const float* __restrict__ Wenc,
    const float* __restrict__ x, const float* __restrict__ b_enc,
    const float* __restrict__ b_pred, const float* __restrict__ h1,
    float* __restrict__ joint, unsigned long long* __restrict__ slot, int t)
{
    int tile = (blockIdx.x & 7)*20 + (blockIdx.x >> 3);
    int nt = tile / 32, bg = tile % 32;
    int lane = threadIdx.x & 63, w = threadIdx.x >> 6;
    int n = nt*128 + w*64 + lane, b0 = bg*4;
    float acc[4] = {0.f,0.f,0.f,0.f};
    const float* wr  = Wpred + (size_t)n*HH;
    const float* wr2 = Wenc  + (size_t)n*HH;
    for (int kc=0; kc<HH; kc+=16){
        float wv[16], wv2[16];
        #pragma unroll
        for (int q=0;q<4;q++){
            float4 f = *reinterpret_cast<const float4*>(wr + kc + q*4);
            wv[q*4+0]=f.x; wv[q*4+1]=f.y; wv[q*4+2]=f.z; wv[q*4+3]=f.w;
            float4 f2 = *reinterpret_cast<const float4*>(wr2 + kc + q*4);
            wv2[q*4+0]=f2.x; wv2[q*4+1]=f2.y; wv2[q*4+2]=f2.z; wv2[q*4+3]=f2.w;
        }
        #pragma unroll
        for (int bi=0; bi<4; ++bi){
            int b = b0+bi;
            const float* hp = h1 + (size_t)b*HH + kc;
            float a = acc[bi];
            #pragma unroll
            for (int k=0;k<16;k++) a = fmaf(hp[k], wv[k], a);
            const float* xp = x + (size_t)b*HH*TT + (size_t)kc*TT + t;
            #pragma unroll
            for (int k=0;k<16;k++) a = fmaf(xp[(size_t)k*TT], wv2[k], a);
            acc[bi] = a;
        }
    }
    #pragma unroll
    for (int bi=0; bi<4; ++bi){
        int b = b0+bi;
        joint[(size_t)b*HH + n] = fmaxf(acc[bi] + b_pred[n] + b_enc[n], 0.0f);
    }
    if (tile == 0) slot[threadIdx.x] = 0ULL;
}

__global__ __launch_bounds__(256) void k_p3o(
    const float* __restrict__ Wout, const float* __restrict__ b_out,
    const float* __restrict__ joint, unsigned long long* __restrict__ slot)
{
    int tile = (blockIdx.x & 7)*34 + (blockIdx.x >> 3);
    int vt = tile >> 4, bg = tile & 15;
    int lane = threadIdx.x & 63, w = threadIdx.x >> 6;
    int v = vt*256 + w*64 + lane;
    bool valid = v < VV;
    int vv = valid ? v : (VV-1);
    int b0 = bg*8;
    float acc[8];
    #pragma unroll
    for (int i=0;i<8;i++) acc[i]=0.f;
    const float* wr = Wout + (size_t)vv*HH;
    for (int kc=0; kc<HH; kc+=16){
        float wv[16];
        #pragma unroll
        for (int q=0;q<4;q++){
            float4 f = *reinterpret_cast<const float4*>(wr + kc + q*4);
            wv[q*4+0]=f.x; wv[q*4+1]=f.y; wv[q*4+2]=f.z; wv[q*4+3]=f.w;
        }
        #pragma unroll
        for (int bi=0; bi<8; ++bi){
            int b = b0+bi;
            const float* jp = joint + (size_t)b*HH + kc;
            float a = acc[bi];
            #pragma unroll
            for (int k=0;k<16;k++) a = fmaf(jp[k], wv[k], a);
            acc[bi] = a;
        }
    }
    float bofl = b_out[vv];
    __shared__ unsigned long long redo[4][8];
    #pragma unroll
    for (int bi=0; bi<8; ++bi){
        unsigned long long key = valid ? packkey(acc[bi] + bofl, (unsigned)v) : 0ULL;
        #pragma unroll
        for (int off=32; off>0; off>>=1){
            unsigned long long o = __shfl_xor(key, off, 64);
            if (o > key) key = o;
        }
        if (lane == 0) redo[w][bi] = key;
    }
    __syncthreads();
    if (threadIdx.x < 8){
        int bi = threadIdx.x;
        unsigned long long m = redo[0][bi];
        #pragma unroll
        for (int q=1;q<4;q++) if (redo[q][bi] > m) m = redo[q][bi];
        atomicMax(&slot[b0+bi], m);
    }
}

__global__ __launch_bounds__(256) void k_finalo(const int* __restrict__ lens,
                        const unsigned long long* __restrict__ slot,
                        const float* __restrict__ hs_r, const float* __restrict__ h1_r,
                        const float* __restrict__ cso,  const float* __restrict__ c1o,
                        float* __restrict__ dout)
{
    int i = blockIdx.x*256 + threadIdx.x;
    if (i >= BB*HH) return;
    int b = i / HH;
    unsigned long long key = slot[b];
    int k = (int)(~(unsigned)key);
    bool m = ((TT-1) >= lens[b]) || (k == 0);
    dout[BB*TT + i]         = m ? hs_r[i] : h1_r[i];
    dout[BB*TT + BB*HH + i] = m ? cso[i]  : c1o[i];
    if (i < BB){
        unsigned long long key2 = slot[i];
        int k2 = (int)(~(unsigned)key2);
        bool mm = ((TT-1) >= lens[i]) || (k2 == 0);
        dout[(size_t)i*TT + (TT-1)] = mm ? 0.0f : (float)k2;
    }
}

extern "C" void kernel_launch(void* const* d_in, const int* in_sizes, int n_in,
                              void* d_out, int out_size, void* d_ws, size_t ws_size,
                              hipStream_t stream)
{
    const float* x     = (const float*)d_in[0];
    const int*   lens  = (const int*)  d_in[1];
    const float* emb   = (const float*)d_in[2];
    const float* Wih   = (const float*)d_in[3];
    const float* Whh   = (const float*)d_in[4];
    const float* bih   = (const float*)d_in[5];
    const float* bhh   = (const float*)d_in[6];
    const float* Wenc  = (const float*)d_in[7];
    const float* benc  = (const float*)d_in[8];
    const float* Wpred = (const float*)d_in[9];
    const float* bpred = (const float*)d_in[10];
    const float* Wout  = (const float*)d_in[11];
    const float* bout  = (const float*)d_in[12];
    const float* h0    = (const float*)d_in[13];
    const float* c0    = (const float*)d_in[14];
    float* out = (float*)d_out;
    (void)in_sizes; (void)n_in; (void)out_size;

    char* ws = (char*)d_ws;
    size_t off = 0;
    auto alloc = [&](size_t bytes) -> void* {
        void* p = ws + off; off += (bytes + 255) & ~(size_t)255; return p;
    };
    const size_t SB = (size_t)HH*BB*sizeof(float);   // 327KB
    float* gA   = (float*)alloc(SB*4);
    float* gB   = (float*)alloc(SB*4);
    float* cA   = (float*)alloc(SB);
    float* cB   = (float*)alloc(SB);
    float* hA   = (float*)alloc(SB);
    float* h1G  = (float*)alloc(SB);
    float* jointG = (float*)alloc(SB);
    unsigned long long* slot = (unsigned long long*)alloc(BB*sizeof(unsigned long long));
    int* label = (int*)alloc(BB*sizeof(int));
    int* ctrl  = (int*)alloc(2048*sizeof(int));
    float* boutP = (float*)alloc((size_t)NC3p*sizeof(float));
    char* region = (char*)alloc(19660800);     // temps, then WJ+WoutK4
    float* embproj  = (float*)alloc((size_t)(VV+1)*G4*sizeof(float));
    float* encprojT = (float*)alloc((size_t)TT*BB*HH*sizeof(float));
    size_t need = off;

    if (ws_size >= need){
        float* WihT  = (float*)(region);
        float* embT  = (float*)(region + 6553600);
        float* WencT = (float*)(region + 17080320);
        float* WJ     = (float*)(region);
        float* WoutK4 = (float*)(region + 8519680);

        k_init5<<<(BB*HH+255)/256, 256, 0, stream>>>(h0, c0, hA, cA, label, slot, ctrl);
        k_tr_gate<<<(G4*160+255)/256, 256, 0, stream>>>(Wih, WihT);
        k_tr_embT<<<(160*VE+255)/256, 256, 0, stream>>>(emb, embT);
        k_tr640<<<(HH*160+255)/256, 256, 0, stream>>>(Wenc, WencT);
        k_embproj3<<<17*160, 256, 0, stream>>>(embT, WihT, bih, bhh, embproj);
        k_encprojT2<<<20480, 128, 0, stream>>>(x, WencT, benc, encprojT);
        k_tr_WJp<<<(NC2p*160+255)/256, 256, 0, stream>>>(Whh, Wpred, WJ);
        k_tr_woutp<<<(NC3p*160+255)/256, 256, 0, stream>>>(Wout, WoutK4);
        k_boutp<<<(NC3p+255)/256, 256, 0, stream>>>(bout, boutP);
        k_gA0<<<80, 512, 0, stream>>>(WJ, h0, gA);

        const float* a0 = WJ;      const float* a1 = WoutK4;
        const float* a2 = bpred;   const float* a3 = boutP;
        const float* a4 = embproj; const float* a5 = encprojT;
        const int*   a6 = lens;
        float* a7 = gA;  float* a8 = gB;
        float* a9 = cA;  float* a10 = cB; float* a11 = hA;
        float* a12 = h1G; float* a13 = jointG;
        unsigned long long* a14 = slot; int* a15 = label;
        int* a16 = ctrl; float* a17 = out;
        void* args[] = {&a0,&a1,&a2,&a3,&a4,&a5,&a6,&a7,&a8,&a9,&a10,&a11,
                        &a12,&a13,&a14,&a15,&a16,&a17};
        hipLaunchCooperativeKernel((const void*)k_run2, dim3(256), dim3(512), args, 0, stream);
        kFin3<<<(BB*HH+255)/256, 256, 0, stream>>>(lens, slot, hA, h1G, cA, cB, out);
        return;
    }

    // -------- fallback: basic per-step path (small ws) --------
    {
        size_t foff = 0;
        auto falloc = [&](size_t bytes) -> void* {
            void* p = ws + foff; foff += (bytes + 255) & ~(size_t)255; return p;
        };
        const size_t BH = (size_t)BB*HH*sizeof(float);
        float* hs0  = (float*)falloc(BH);
        float* hs1  = (float*)falloc(BH);
        float* h1b0 = (float*)falloc(BH);
        float* h1b1 = (float*)falloc(BH);
        float* cso  = (float*)falloc(BH);
        float* c1o  = (float*)falloc(BH);
        float* joint= (float*)falloc(BH);
        int* labelf = (int*)falloc(BB*sizeof(int));
        unsigned long long* slotf = (unsigned long long*)falloc(BB*sizeof(unsigned long long));

        k_init<<<(BB*HH+255)/256, 256, 0, stream>>>(h0, c0, hs0, cso, labelf, slotf);
        float* hsbuf[2] = {hs0, hs1};
        float* h1buf[2] = {h1b0, h1b1};
        for (int t = 0; t < TT; ++t){
            const float* hsr = hsbuf[t & 1];
            float*       hsw = hsbuf[(t+1) & 1];
            const float* h1r = h1buf[(t+1) & 1];
            float*       h1w = h1buf[t & 1];
            k_p1o<<<160, 256, 0, stream>>>(Whh, Wih, emb, bih, bhh, lens,
                                           hsr, hsw, h1r, h1w, cso, c1o, labelf, slotf, out, t);
            k_p2o<<<160, 128, 0, stream>>>(Wpred, Wenc, x, benc, bpred, h1w, joint, slotf, t);
            k_p3o<<<272, 256, 0, stream>>>(Wout, bout, joint, slotf);
        }
        k_finalo<<<(BB*HH+255)/256, 256, 0, stream>>>(lens, slotf, hsbuf[0], h1buf[1], cso, c1o, out);
    }
}